// Round 1
// baseline (1501.499 us; speedup 1.0000x reference)
//
#include <hip/hip_runtime.h>
#include <math.h>

// Problem constants (reference: B=2, T=2048, D_MODEL=1024, N_HEAD=16, D_HEAD=64)
constexpr int Bb   = 2;
constexpr int T    = 2048;
constexpr int C    = 1024;
constexpr int H    = 16;
constexpr int DH   = 64;
constexpr int M    = Bb * T;   // 4096 rows
constexpr int NQKV = 3 * C;    // 3072

// ---------------------------------------------------------------------------
// out[M,N] = A[M,K] @ W[K,N] + bias[N]     (fp32, 64x64 tile, BK=16, 4x4/thread)
// ---------------------------------------------------------------------------
__global__ __launch_bounds__(256)
void gemm_bias_f32(const float* __restrict__ A, const float* __restrict__ W,
                   const float* __restrict__ bias, float* __restrict__ out,
                   int Ndim, int Kdim)
{
    __shared__ __align__(16) float As[16][68];  // [k][m], +4 pad keeps 16B align, kills conflicts
    __shared__ __align__(16) float Bs[16][64];  // [k][n]

    const int tid = threadIdx.x;
    const int tx  = tid & 15;       // n-dir
    const int ty  = tid >> 4;       // m-dir
    const int m0  = blockIdx.y * 64;
    const int n0  = blockIdx.x * 64;

    // A-tile load mapping: 4 consecutive floats along K per thread
    const int ar = tid >> 2;          // 0..63 row in tile
    const int ac = (tid & 3) << 2;    // 0,4,8,12 col in K-tile
    // B-tile load mapping: 4 consecutive floats along N per thread
    const int br = tid >> 4;          // 0..15
    const int bc = (tid & 15) << 2;   // 0..60

    float acc[4][4] = {};

    for (int k0 = 0; k0 < Kdim; k0 += 16) {
        const float4 av = *(const float4*)(A + (size_t)(m0 + ar) * Kdim + k0 + ac);
        const float4 bv = *(const float4*)(W + (size_t)(k0 + br) * Ndim + n0 + bc);
        __syncthreads();
        As[ac + 0][ar] = av.x;
        As[ac + 1][ar] = av.y;
        As[ac + 2][ar] = av.z;
        As[ac + 3][ar] = av.w;
        *(float4*)&Bs[br][bc] = bv;
        __syncthreads();
#pragma unroll
        for (int k = 0; k < 16; ++k) {
            const float4 a = *(const float4*)&As[k][ty << 2];
            const float4 b = *(const float4*)&Bs[k][tx << 2];
            acc[0][0] += a.x * b.x; acc[0][1] += a.x * b.y; acc[0][2] += a.x * b.z; acc[0][3] += a.x * b.w;
            acc[1][0] += a.y * b.x; acc[1][1] += a.y * b.y; acc[1][2] += a.y * b.z; acc[1][3] += a.y * b.w;
            acc[2][0] += a.z * b.x; acc[2][1] += a.z * b.y; acc[2][2] += a.z * b.z; acc[2][3] += a.z * b.w;
            acc[3][0] += a.w * b.x; acc[3][1] += a.w * b.y; acc[3][2] += a.w * b.z; acc[3][3] += a.w * b.w;
        }
    }

    const float4 bb = *(const float4*)(bias + n0 + (tx << 2));
#pragma unroll
    for (int i = 0; i < 4; ++i) {
        float4 r;
        r.x = acc[i][0] + bb.x;
        r.y = acc[i][1] + bb.y;
        r.z = acc[i][2] + bb.z;
        r.w = acc[i][3] + bb.w;
        *(float4*)(out + (size_t)(m0 + (ty << 2) + i) * Ndim + n0 + (tx << 2)) = r;
    }
}

// ---------------------------------------------------------------------------
// Causal attention, flash-style online softmax, fp32.
// qkv layout: [B, T, 3*C] with per-row offsets  q: +0, k: +C, v: +2C,
// head h occupies [h*64, h*64+64).
// Block: 256 threads = 64 q-rows x 4 lanes; lane-chunk c owns dims [16c,16c+16).
// Grid: (T/64, B*H).
// Output att: [B, T, C] row-major (head-concat), ready for the proj GEMM.
// ---------------------------------------------------------------------------
__global__ __launch_bounds__(256)
void attn_causal_f32(const float* __restrict__ qkv, float* __restrict__ att)
{
    __shared__ __align__(16) float Ks[64][68];  // +4 pad: conflict-free b128 writes
    __shared__ __align__(16) float Vs[64][68];

    const int tid = threadIdx.x;
    const int bh  = blockIdx.y;          // 0..31
    const int b   = bh >> 4;
    const int h   = bh & 15;
    const int qt  = blockIdx.x;          // 0..T/64-1
    const int lr  = tid >> 2;            // 0..63 (q-row within tile / load row)
    const int c   = tid & 3;             // dim chunk
    const int lc  = c << 4;              // dim base
    const int r   = qt * 64 + lr;        // absolute query row

    const float* base = qkv + (size_t)b * T * 3072 + h * 64;
    const float* Qp = base;
    const float* Kp = base + 1024;
    const float* Vp = base + 2048;

    // this thread's 16-dim slice of its query row
    float q[16];
    {
        const float* qp = Qp + (size_t)r * 3072 + lc;
        *(float4*)&q[0]  = *(const float4*)(qp + 0);
        *(float4*)&q[4]  = *(const float4*)(qp + 4);
        *(float4*)&q[8]  = *(const float4*)(qp + 8);
        *(float4*)&q[12] = *(const float4*)(qp + 12);
    }

    float o[16];
#pragma unroll
    for (int i = 0; i < 16; ++i) o[i] = 0.f;
    float mmax = -INFINITY;
    float l = 0.f;

    for (int j0 = 0; j0 <= qt * 64; j0 += 64) {
        __syncthreads();
        {
            const float* kp = Kp + (size_t)(j0 + lr) * 3072 + lc;
            const float* vp = Vp + (size_t)(j0 + lr) * 3072 + lc;
            *(float4*)&Ks[lr][lc + 0]  = *(const float4*)(kp + 0);
            *(float4*)&Ks[lr][lc + 4]  = *(const float4*)(kp + 4);
            *(float4*)&Ks[lr][lc + 8]  = *(const float4*)(kp + 8);
            *(float4*)&Ks[lr][lc + 12] = *(const float4*)(kp + 12);
            *(float4*)&Vs[lr][lc + 0]  = *(const float4*)(vp + 0);
            *(float4*)&Vs[lr][lc + 4]  = *(const float4*)(vp + 4);
            *(float4*)&Vs[lr][lc + 8]  = *(const float4*)(vp + 8);
            *(float4*)&Vs[lr][lc + 12] = *(const float4*)(vp + 12);
        }
        __syncthreads();

        const int jmax = min(64, r - j0 + 1);   // causal bound within this key tile
        for (int j = 0; j < jmax; ++j) {
            const float* kr = &Ks[j][lc];
            float s = 0.f;
#pragma unroll
            for (int i = 0; i < 16; ++i) s += q[i] * kr[i];
            // reduce partial dot across the 4 lanes of this q-row
            s += __shfl_xor(s, 1);
            s += __shfl_xor(s, 2);
            s *= 0.125f;   // 1/sqrt(64)

            const float mn   = fmaxf(mmax, s);
            const float corr = __expf(mmax - mn);   // exp(-inf)=0 handles first key
            const float p    = __expf(s - mn);
            l = l * corr + p;
            const float* vr = &Vs[j][lc];
#pragma unroll
            for (int i = 0; i < 16; ++i) o[i] = o[i] * corr + p * vr[i];
            mmax = mn;
        }
    }

    const float inv = 1.f / l;
    float res[16];
#pragma unroll
    for (int i = 0; i < 16; ++i) res[i] = o[i] * inv;
    float* op = att + ((size_t)(b * T + r)) * 1024 + h * 64 + lc;
    *(float4*)(op + 0)  = *(float4*)&res[0];
    *(float4*)(op + 4)  = *(float4*)&res[4];
    *(float4*)(op + 8)  = *(float4*)&res[8];
    *(float4*)(op + 12) = *(float4*)&res[12];
}

// ---------------------------------------------------------------------------
extern "C" void kernel_launch(void* const* d_in, const int* in_sizes, int n_in,
                              void* d_out, int out_size, void* d_ws, size_t ws_size,
                              hipStream_t stream)
{
    const float* x      = (const float*)d_in[0];   // [B,T,C]
    const float* w_qkv  = (const float*)d_in[1];   // [C,3C]
    const float* b_qkv  = (const float*)d_in[2];   // [3C]
    const float* w_proj = (const float*)d_in[3];   // [C,C]
    const float* b_proj = (const float*)d_in[4];   // [C]
    float* out = (float*)d_out;                    // [B,T,C]

    float* qkvbuf = (float*)d_ws;                        // M x 3072 fp32 (48 MB)
    float* attbuf = qkvbuf + (size_t)M * NQKV;           // M x 1024 fp32 (16 MB)

    // 1) qkv = x @ w_qkv + b_qkv
    gemm_bias_f32<<<dim3(NQKV / 64, M / 64), 256, 0, stream>>>(x, w_qkv, b_qkv, qkvbuf, NQKV, C);
    // 2) causal attention per (b,h), flash-style
    attn_causal_f32<<<dim3(T / 64, Bb * H), 256, 0, stream>>>(qkvbuf, attbuf);
    // 3) out = att @ w_proj + b_proj
    gemm_bias_f32<<<dim3(C / 64, M / 64), 256, 0, stream>>>(attbuf, w_proj, b_proj, out, C, C);
}

// Round 2
// 766.018 us; speedup vs baseline: 1.9601x; 1.9601x over previous
//
#include <hip/hip_runtime.h>
#include <hip/hip_bf16.h>
#include <math.h>

// Problem constants (reference: B=2, T=2048, D_MODEL=1024, N_HEAD=16, D_HEAD=64)
constexpr int Bb   = 2;
constexpr int T    = 2048;
constexpr int C    = 1024;
constexpr int H    = 16;
constexpr int M    = Bb * T;   // 4096 rows
constexpr int NQKV = 3 * C;    // 3072

typedef __attribute__((ext_vector_type(8))) short bf16x8;
typedef __attribute__((ext_vector_type(4))) float f32x4;

__device__ inline short f2bf(float f) {
    __hip_bfloat16 h = __float2bfloat16(f);
    return *reinterpret_cast<short*>(&h);
}

// ---------------------------------------------------------------------------
// out[M,N] = A[M,K] @ W[K,N] + bias[N]     (fp32, 64x64 tile, BK=16, 4x4/thread)
// (unchanged from round 1 — validated)
// ---------------------------------------------------------------------------
__global__ __launch_bounds__(256)
void gemm_bias_f32(const float* __restrict__ A, const float* __restrict__ W,
                   const float* __restrict__ bias, float* __restrict__ out,
                   int Ndim, int Kdim)
{
    __shared__ __align__(16) float As[16][68];
    __shared__ __align__(16) float Bs[16][64];

    const int tid = threadIdx.x;
    const int tx  = tid & 15;
    const int ty  = tid >> 4;
    const int m0  = blockIdx.y * 64;
    const int n0  = blockIdx.x * 64;

    const int ar = tid >> 2;
    const int ac = (tid & 3) << 2;
    const int br = tid >> 4;
    const int bc = (tid & 15) << 2;

    float acc[4][4] = {};

    for (int k0 = 0; k0 < Kdim; k0 += 16) {
        const float4 av = *(const float4*)(A + (size_t)(m0 + ar) * Kdim + k0 + ac);
        const float4 bv = *(const float4*)(W + (size_t)(k0 + br) * Ndim + n0 + bc);
        __syncthreads();
        As[ac + 0][ar] = av.x;
        As[ac + 1][ar] = av.y;
        As[ac + 2][ar] = av.z;
        As[ac + 3][ar] = av.w;
        *(float4*)&Bs[br][bc] = bv;
        __syncthreads();
#pragma unroll
        for (int k = 0; k < 16; ++k) {
            const float4 a = *(const float4*)&As[k][ty << 2];
            const float4 b = *(const float4*)&Bs[k][tx << 2];
            acc[0][0] += a.x * b.x; acc[0][1] += a.x * b.y; acc[0][2] += a.x * b.z; acc[0][3] += a.x * b.w;
            acc[1][0] += a.y * b.x; acc[1][1] += a.y * b.y; acc[1][2] += a.y * b.z; acc[1][3] += a.y * b.w;
            acc[2][0] += a.z * b.x; acc[2][1] += a.z * b.y; acc[2][2] += a.z * b.z; acc[2][3] += a.z * b.w;
            acc[3][0] += a.w * b.x; acc[3][1] += a.w * b.y; acc[3][2] += a.w * b.z; acc[3][3] += a.w * b.w;
        }
    }

    const float4 bb = *(const float4*)(bias + n0 + (tx << 2));
#pragma unroll
    for (int i = 0; i < 4; ++i) {
        float4 r;
        r.x = acc[i][0] + bb.x;
        r.y = acc[i][1] + bb.y;
        r.z = acc[i][2] + bb.z;
        r.w = acc[i][3] + bb.w;
        *(float4*)(out + (size_t)(m0 + (ty << 2) + i) * Ndim + n0 + (tx << 2)) = r;
    }
}

// ---------------------------------------------------------------------------
// MFMA flash attention (bf16 compute, fp32 accumulate/softmax).
// Block = 256 threads = 4 waves. Wave w owns q-rows [qt*64+w*16, +16).
// Grid: (T/64, B*H).
// K staged [key][d] bf16 (LD=72, 16B-aligned rows); V staged transposed
// Vt[d][key]; P round-trips through per-wave LDS (C-layout -> A-layout).
// ---------------------------------------------------------------------------
constexpr int LDK = 72;   // padded LDS leading dim (bf16 elems), 144 B rows

__global__ __launch_bounds__(256)
void attn_mfma(const float* __restrict__ qkv, float* __restrict__ att)
{
    __shared__ __align__(16) short Ks[64 * LDK];       // K tile [key][d]
    __shared__ __align__(16) short Vt[64 * LDK];       // V tile transposed [d][key]
    __shared__ __align__(16) short Ps[4][16 * LDK];    // per-wave P buffer [q][key]

    const int tid = threadIdx.x;
    const int w   = tid >> 6;        // wave 0..3
    const int l   = tid & 63;        // lane
    const int lk  = l & 15;          // frag row/col index
    const int lq  = l >> 4;          // frag quad 0..3
    const int b   = blockIdx.y >> 4;
    const int h   = blockIdx.y & 15;
    const int qt  = blockIdx.x;

    const float* base = qkv + (size_t)b * T * 3072 + h * 64;

    // --- Q fragments (A-operand: Q[m=lk][k=lq*8+j]), loaded once ---
    bf16x8 qf0, qf1;
    {
        const float* qp = base + (size_t)(qt * 64 + w * 16 + lk) * 3072;
#pragma unroll
        for (int j = 0; j < 8; ++j) {
            qf0[j] = f2bf(qp[lq * 8 + j]);
            qf1[j] = f2bf(qp[32 + lq * 8 + j]);
        }
    }

    f32x4 acc_o[4];
#pragma unroll
    for (int dt = 0; dt < 4; ++dt) acc_o[dt] = (f32x4){0.f, 0.f, 0.f, 0.f};
    float m_r[4] = {-INFINITY, -INFINITY, -INFINITY, -INFINITY};
    float l_r[4] = {0.f, 0.f, 0.f, 0.f};

    // staging assignment: thread handles key=tid&63, dims [(tid>>6)*16, +16)
    const int skey = tid & 63;
    const int sd4  = (tid >> 6) * 16;

    for (int j0 = 0; j0 <= qt * 64; j0 += 64) {
        __syncthreads();
        {
            const float* kp = base + 1024 + (size_t)(j0 + skey) * 3072 + sd4;
            const float* vp = kp + 1024;
#pragma unroll
            for (int i = 0; i < 16; i += 4) {
                const float4 kv = *(const float4*)(kp + i);
                const float4 vv = *(const float4*)(vp + i);
                unsigned int p0 = (unsigned int)(unsigned short)f2bf(kv.x)
                                | ((unsigned int)(unsigned short)f2bf(kv.y) << 16);
                unsigned int p1 = (unsigned int)(unsigned short)f2bf(kv.z)
                                | ((unsigned int)(unsigned short)f2bf(kv.w) << 16);
                *(unsigned int*)&Ks[skey * LDK + sd4 + i]     = p0;
                *(unsigned int*)&Ks[skey * LDK + sd4 + i + 2] = p1;
                Vt[(sd4 + i + 0) * LDK + skey] = f2bf(vv.x);
                Vt[(sd4 + i + 1) * LDK + skey] = f2bf(vv.y);
                Vt[(sd4 + i + 2) * LDK + skey] = f2bf(vv.z);
                Vt[(sd4 + i + 3) * LDK + skey] = f2bf(vv.w);
            }
        }
        __syncthreads();

        // --- S = Q K^T for 4 key-subtiles of 16 ---
        f32x4 s[4];
#pragma unroll
        for (int kt = 0; kt < 4; ++kt) {
            const bf16x8 kf0 = *(const bf16x8*)&Ks[(kt * 16 + lk) * LDK + lq * 8];
            const bf16x8 kf1 = *(const bf16x8*)&Ks[(kt * 16 + lk) * LDK + 32 + lq * 8];
            f32x4 a = (f32x4){0.f, 0.f, 0.f, 0.f};
            a = __builtin_amdgcn_mfma_f32_16x16x32_bf16(qf0, kf0, a, 0, 0, 0);
            a = __builtin_amdgcn_mfma_f32_16x16x32_bf16(qf1, kf1, a, 0, 0, 0);
            s[kt] = a;
        }

        // --- scale + causal mask (diagonal tile only) ---
        const bool diag = (j0 == qt * 64);
#pragma unroll
        for (int kt = 0; kt < 4; ++kt) {
#pragma unroll
            for (int r = 0; r < 4; ++r) {
                float sv = s[kt][r] * 0.125f;
                if (diag && (kt * 16 + lk > w * 16 + lq * 4 + r)) sv = -1e30f;
                s[kt][r] = sv;
            }
        }

        // --- online softmax (rows live across 16 lanes; reduce via shfl_xor) ---
        float corr[4];
#pragma unroll
        for (int r = 0; r < 4; ++r) {
            float mx = fmaxf(fmaxf(s[0][r], s[1][r]), fmaxf(s[2][r], s[3][r]));
            mx = fmaxf(mx, __shfl_xor(mx, 1));
            mx = fmaxf(mx, __shfl_xor(mx, 2));
            mx = fmaxf(mx, __shfl_xor(mx, 4));
            mx = fmaxf(mx, __shfl_xor(mx, 8));
            const float mn = fmaxf(m_r[r], mx);
            corr[r] = __expf(m_r[r] - mn);
            m_r[r]  = mn;
            float ps = 0.f;
#pragma unroll
            for (int kt = 0; kt < 4; ++kt) {
                const float p = __expf(s[kt][r] - mn);
                s[kt][r] = p;
                ps += p;
            }
            ps += __shfl_xor(ps, 1);
            ps += __shfl_xor(ps, 2);
            ps += __shfl_xor(ps, 4);
            ps += __shfl_xor(ps, 8);
            l_r[r] = l_r[r] * corr[r] + ps;
        }

        // --- P: C-layout -> LDS -> A-layout (per-wave private, no barrier) ---
        short* myP = &Ps[w][0];
#pragma unroll
        for (int kt = 0; kt < 4; ++kt) {
#pragma unroll
            for (int r = 0; r < 4; ++r)
                myP[(lq * 4 + r) * LDK + kt * 16 + lk] = f2bf(s[kt][r]);
        }

        // rescale O accumulators
#pragma unroll
        for (int dt = 0; dt < 4; ++dt) {
#pragma unroll
            for (int r = 0; r < 4; ++r) acc_o[dt][r] *= corr[r];
        }

        // --- O += P V  (k = 64 keys as two 32-key chunks) ---
#pragma unroll
        for (int kc = 0; kc < 2; ++kc) {
            const bf16x8 pf = *(const bf16x8*)&myP[lk * LDK + kc * 32 + lq * 8];
#pragma unroll
            for (int dt = 0; dt < 4; ++dt) {
                const bf16x8 vf = *(const bf16x8*)&Vt[(dt * 16 + lk) * LDK + kc * 32 + lq * 8];
                acc_o[dt] = __builtin_amdgcn_mfma_f32_16x16x32_bf16(pf, vf, acc_o[dt], 0, 0, 0);
            }
        }
    }

    // --- epilogue: normalize, store fp32 [B,T,C] head-concat ---
    float* op = att + ((size_t)(b * T + qt * 64 + w * 16)) * 1024 + h * 64;
#pragma unroll
    for (int r = 0; r < 4; ++r) {
        const float inv = 1.f / l_r[r];
#pragma unroll
        for (int dt = 0; dt < 4; ++dt)
            op[(size_t)(lq * 4 + r) * 1024 + dt * 16 + lk] = acc_o[dt][r] * inv;
    }
}

// ---------------------------------------------------------------------------
extern "C" void kernel_launch(void* const* d_in, const int* in_sizes, int n_in,
                              void* d_out, int out_size, void* d_ws, size_t ws_size,
                              hipStream_t stream)
{
    const float* x      = (const float*)d_in[0];
    const float* w_qkv  = (const float*)d_in[1];
    const float* b_qkv  = (const float*)d_in[2];
    const float* w_proj = (const float*)d_in[3];
    const float* b_proj = (const float*)d_in[4];
    float* out = (float*)d_out;

    float* qkvbuf = (float*)d_ws;                  // M x 3072 fp32
    float* attbuf = qkvbuf + (size_t)M * NQKV;     // M x 1024 fp32

    gemm_bias_f32<<<dim3(NQKV / 64, M / 64), 256, 0, stream>>>(x, w_qkv, b_qkv, qkvbuf, NQKV, C);
    attn_mfma<<<dim3(T / 64, Bb * H), 256, 0, stream>>>(qkvbuf, attbuf);
    gemm_bias_f32<<<dim3(C / 64, M / 64), 256, 0, stream>>>(attbuf, w_proj, b_proj, out, C, C);
}

// Round 3
// 280.607 us; speedup vs baseline: 5.3509x; 2.7299x over previous
//
#include <hip/hip_runtime.h>
#include <hip/hip_bf16.h>
#include <math.h>

// Problem constants (reference: B=2, T=2048, D_MODEL=1024, N_HEAD=16, D_HEAD=64)
constexpr int Bb   = 2;
constexpr int T    = 2048;
constexpr int C    = 1024;
constexpr int H    = 16;
constexpr int M    = Bb * T;   // 4096 rows
constexpr int NQKV = 3 * C;    // 3072

typedef __attribute__((ext_vector_type(8))) short bf16x8;
typedef __attribute__((ext_vector_type(4))) float f32x4;

__device__ inline short f2bf(float f) {
    __hip_bfloat16 h = __float2bfloat16(f);
    return *reinterpret_cast<short*>(&h);
}

// ---------------------------------------------------------------------------
// fp32 -> bf16 elementwise
// ---------------------------------------------------------------------------
__global__ __launch_bounds__(256)
void cvt_bf16(const float* __restrict__ x, short* __restrict__ y, int n)
{
    int i = (blockIdx.x * 256 + threadIdx.x) * 4;
    if (i < n) {
        const float4 v = *(const float4*)(x + i);
        short4 s;
        s.x = f2bf(v.x); s.y = f2bf(v.y); s.z = f2bf(v.z); s.w = f2bf(v.w);
        *(short4*)(y + i) = s;
    }
}

// ---------------------------------------------------------------------------
// W[K][N] fp32  ->  Wt[N][K] bf16   (32x32 LDS tile transpose)
// ---------------------------------------------------------------------------
__global__ __launch_bounds__(256)
void transpose_cvt(const float* __restrict__ W, short* __restrict__ Wt, int K, int N)
{
    __shared__ float tile[32][33];
    const int n0 = blockIdx.x * 32, k0 = blockIdx.y * 32;
    const int tx = threadIdx.x, ty = threadIdx.y;   // 32 x 8
#pragma unroll
    for (int i = 0; i < 32; i += 8)
        tile[ty + i][tx] = W[(size_t)(k0 + ty + i) * N + n0 + tx];
    __syncthreads();
#pragma unroll
    for (int i = 0; i < 32; i += 8)
        Wt[(size_t)(n0 + ty + i) * K + k0 + tx] = f2bf(tile[tx][ty + i]);
}

// ---------------------------------------------------------------------------
// out[M,N] = A[M,K] @ Bt[N,K]^T + bias[N]   (bf16 MFMA, 128x128 tile, BK=32)
// 4 waves, each computes a 64x64 subtile as 4x4 mfma_f32_16x16x32_bf16.
// A-frag = A[m=lk][k=lq*8+j]; B-frag = Bt[n=lk][k=lq*8+j]  (HW-validated R2).
// C-layout: col=lane&15, row=quad*4+reg.
// ---------------------------------------------------------------------------
constexpr int LDT = 40;   // LDS leading dim (bf16 elems), 80 B rows -> ~2-way max

template<bool OUT_BF16>
__global__ __launch_bounds__(256)
void gemm_mfma(const short* __restrict__ A, const short* __restrict__ Bt,
               const float* __restrict__ bias, void* __restrict__ outp,
               int Ndim, int Kdim)
{
    __shared__ __align__(16) short As[128 * LDT];
    __shared__ __align__(16) short Bs[128 * LDT];

    const int tid = threadIdx.x;
    const int w   = tid >> 6;
    const int l   = tid & 63;
    const int lk  = l & 15;
    const int lq  = l >> 4;
    const int m0  = blockIdx.y * 128, n0 = blockIdx.x * 128;
    const int mw  = (w >> 1) * 64, nw = (w & 1) * 64;
    const int sr  = tid >> 2;          // staging row 0..63 (and +64)
    const int sc  = (tid & 3) * 8;     // staging k-chunk

    f32x4 acc[4][4];
#pragma unroll
    for (int i = 0; i < 4; ++i)
#pragma unroll
        for (int j = 0; j < 4; ++j) acc[i][j] = (f32x4){0.f, 0.f, 0.f, 0.f};

    for (int k0 = 0; k0 < Kdim; k0 += 32) {
        const bf16x8 a0 = *(const bf16x8*)(A  + (size_t)(m0 + sr)      * Kdim + k0 + sc);
        const bf16x8 a1 = *(const bf16x8*)(A  + (size_t)(m0 + sr + 64) * Kdim + k0 + sc);
        const bf16x8 b0 = *(const bf16x8*)(Bt + (size_t)(n0 + sr)      * Kdim + k0 + sc);
        const bf16x8 b1 = *(const bf16x8*)(Bt + (size_t)(n0 + sr + 64) * Kdim + k0 + sc);
        __syncthreads();
        *(bf16x8*)&As[sr * LDT + sc]        = a0;
        *(bf16x8*)&As[(sr + 64) * LDT + sc] = a1;
        *(bf16x8*)&Bs[sr * LDT + sc]        = b0;
        *(bf16x8*)&Bs[(sr + 64) * LDT + sc] = b1;
        __syncthreads();

        bf16x8 af[4], bfr[4];
#pragma unroll
        for (int mt = 0; mt < 4; ++mt)
            af[mt] = *(const bf16x8*)&As[(mw + mt * 16 + lk) * LDT + lq * 8];
#pragma unroll
        for (int nt = 0; nt < 4; ++nt)
            bfr[nt] = *(const bf16x8*)&Bs[(nw + nt * 16 + lk) * LDT + lq * 8];
#pragma unroll
        for (int mt = 0; mt < 4; ++mt)
#pragma unroll
            for (int nt = 0; nt < 4; ++nt)
                acc[mt][nt] = __builtin_amdgcn_mfma_f32_16x16x32_bf16(af[mt], bfr[nt], acc[mt][nt], 0, 0, 0);
    }

#pragma unroll
    for (int mt = 0; mt < 4; ++mt) {
#pragma unroll
        for (int nt = 0; nt < 4; ++nt) {
            const int col = n0 + nw + nt * 16 + lk;
            const float bv = bias[col];
#pragma unroll
            for (int r = 0; r < 4; ++r) {
                const int row = m0 + mw + mt * 16 + lq * 4 + r;
                const float v = acc[mt][nt][r] + bv;
                if (OUT_BF16) ((short*)outp)[(size_t)row * Ndim + col] = f2bf(v);
                else          ((float*)outp)[(size_t)row * Ndim + col] = v;
            }
        }
    }
}

// ---------------------------------------------------------------------------
// MFMA flash attention, bf16 in / bf16 out (structure validated round 2).
// qkv: [B*T][3072] bf16 (q+0, k+1024, v+2048; head h at h*64).
// att: [B*T][1024] bf16.
// ---------------------------------------------------------------------------
constexpr int LDK = 72;   // 144 B rows (16B-aligned)

__global__ __launch_bounds__(256)
void attn_mfma(const short* __restrict__ qkv, short* __restrict__ att)
{
    __shared__ __align__(16) short Ks[64 * LDK];       // K tile [key][d]
    __shared__ __align__(16) short Vt[64 * LDK];       // V transposed [d][key]
    __shared__ __align__(16) short Ps[4][16 * LDK];    // per-wave P [q][key]

    const int tid = threadIdx.x;
    const int w   = tid >> 6;
    const int l   = tid & 63;
    const int lk  = l & 15;
    const int lq  = l >> 4;
    const int b   = blockIdx.y >> 4;
    const int h   = blockIdx.y & 15;
    const int qt  = blockIdx.x;

    const short* base = qkv + (size_t)b * T * 3072 + h * 64;

    // Q fragments (A-operand), loaded once
    const short* qp = base + (size_t)(qt * 64 + w * 16 + lk) * 3072 + lq * 8;
    const bf16x8 qf0 = *(const bf16x8*)qp;
    const bf16x8 qf1 = *(const bf16x8*)(qp + 32);

    f32x4 acc_o[4];
#pragma unroll
    for (int dt = 0; dt < 4; ++dt) acc_o[dt] = (f32x4){0.f, 0.f, 0.f, 0.f};
    float m_r[4] = {-INFINITY, -INFINITY, -INFINITY, -INFINITY};
    float l_r[4] = {0.f, 0.f, 0.f, 0.f};

    const int skey = tid & 63;
    const int sd4  = (tid >> 6) * 16;

    for (int j0 = 0; j0 <= qt * 64; j0 += 64) {
        __syncthreads();
        {
            const short* kp = base + 1024 + (size_t)(j0 + skey) * 3072 + sd4;
            const short* vp = kp + 1024;
            const bf16x8 kv0 = *(const bf16x8*)kp;
            const bf16x8 kv1 = *(const bf16x8*)(kp + 8);
            const bf16x8 vv0 = *(const bf16x8*)vp;
            const bf16x8 vv1 = *(const bf16x8*)(vp + 8);
            *(bf16x8*)&Ks[skey * LDK + sd4]     = kv0;
            *(bf16x8*)&Ks[skey * LDK + sd4 + 8] = kv1;
#pragma unroll
            for (int j = 0; j < 8; ++j) {
                Vt[(sd4 + j) * LDK + skey]     = vv0[j];
                Vt[(sd4 + 8 + j) * LDK + skey] = vv1[j];
            }
        }
        __syncthreads();

        // S = Q K^T (4 key-subtiles of 16)
        f32x4 s[4];
#pragma unroll
        for (int kt = 0; kt < 4; ++kt) {
            const bf16x8 kf0 = *(const bf16x8*)&Ks[(kt * 16 + lk) * LDK + lq * 8];
            const bf16x8 kf1 = *(const bf16x8*)&Ks[(kt * 16 + lk) * LDK + 32 + lq * 8];
            f32x4 a = (f32x4){0.f, 0.f, 0.f, 0.f};
            a = __builtin_amdgcn_mfma_f32_16x16x32_bf16(qf0, kf0, a, 0, 0, 0);
            a = __builtin_amdgcn_mfma_f32_16x16x32_bf16(qf1, kf1, a, 0, 0, 0);
            s[kt] = a;
        }

        const bool diag = (j0 == qt * 64);
#pragma unroll
        for (int kt = 0; kt < 4; ++kt) {
#pragma unroll
            for (int r = 0; r < 4; ++r) {
                float sv = s[kt][r] * 0.125f;
                if (diag && (kt * 16 + lk > w * 16 + lq * 4 + r)) sv = -1e30f;
                s[kt][r] = sv;
            }
        }

        // online softmax (rows live across 16 lanes)
        float corr[4];
#pragma unroll
        for (int r = 0; r < 4; ++r) {
            float mx = fmaxf(fmaxf(s[0][r], s[1][r]), fmaxf(s[2][r], s[3][r]));
            mx = fmaxf(mx, __shfl_xor(mx, 1));
            mx = fmaxf(mx, __shfl_xor(mx, 2));
            mx = fmaxf(mx, __shfl_xor(mx, 4));
            mx = fmaxf(mx, __shfl_xor(mx, 8));
            const float mn = fmaxf(m_r[r], mx);
            corr[r] = __expf(m_r[r] - mn);
            m_r[r]  = mn;
            float ps = 0.f;
#pragma unroll
            for (int kt = 0; kt < 4; ++kt) {
                const float p = __expf(s[kt][r] - mn);
                s[kt][r] = p;
                ps += p;
            }
            ps += __shfl_xor(ps, 1);
            ps += __shfl_xor(ps, 2);
            ps += __shfl_xor(ps, 4);
            ps += __shfl_xor(ps, 8);
            l_r[r] = l_r[r] * corr[r] + ps;
        }

        // P: C-layout -> per-wave LDS -> A-layout
        short* myP = &Ps[w][0];
#pragma unroll
        for (int kt = 0; kt < 4; ++kt) {
#pragma unroll
            for (int r = 0; r < 4; ++r)
                myP[(lq * 4 + r) * LDK + kt * 16 + lk] = f2bf(s[kt][r]);
        }

#pragma unroll
        for (int dt = 0; dt < 4; ++dt) {
#pragma unroll
            for (int r = 0; r < 4; ++r) acc_o[dt][r] *= corr[r];
        }

        // O += P V
#pragma unroll
        for (int kc = 0; kc < 2; ++kc) {
            const bf16x8 pf = *(const bf16x8*)&myP[lk * LDK + kc * 32 + lq * 8];
#pragma unroll
            for (int dt = 0; dt < 4; ++dt) {
                const bf16x8 vf = *(const bf16x8*)&Vt[(dt * 16 + lk) * LDK + kc * 32 + lq * 8];
                acc_o[dt] = __builtin_amdgcn_mfma_f32_16x16x32_bf16(pf, vf, acc_o[dt], 0, 0, 0);
            }
        }
    }

    // epilogue: normalize, store bf16 [B,T,C] head-concat
    short* op = att + ((size_t)(b * T + qt * 64 + w * 16)) * 1024 + h * 64;
#pragma unroll
    for (int r = 0; r < 4; ++r) {
        const float inv = 1.f / l_r[r];
#pragma unroll
        for (int dt = 0; dt < 4; ++dt)
            op[(size_t)(lq * 4 + r) * 1024 + dt * 16 + lk] = f2bf(acc_o[dt][r] * inv);
    }
}

// ---------------------------------------------------------------------------
extern "C" void kernel_launch(void* const* d_in, const int* in_sizes, int n_in,
                              void* d_out, int out_size, void* d_ws, size_t ws_size,
                              hipStream_t stream)
{
    const float* x      = (const float*)d_in[0];   // [B,T,C]
    const float* w_qkv  = (const float*)d_in[1];   // [C,3C]
    const float* b_qkv  = (const float*)d_in[2];   // [3C]
    const float* w_proj = (const float*)d_in[3];   // [C,C]
    const float* b_proj = (const float*)d_in[4];   // [C]
    float* out = (float*)d_out;                    // [B,T,C] fp32

    short* xb     = (short*)d_ws;                        //  8 MB
    short* wqkvt  = xb     + (size_t)M * C;              //  6 MB  [3072][1024]
    short* wprojt = wqkvt  + (size_t)NQKV * C;           //  2 MB  [1024][1024]
    short* qkvb   = wprojt + (size_t)C * C;              // 24 MB  [4096][3072]
    short* attb   = qkvb   + (size_t)M * NQKV;           //  8 MB  [4096][1024]

    cvt_bf16<<<(M * C) / 1024, 256, 0, stream>>>(x, xb, M * C);
    transpose_cvt<<<dim3(NQKV / 32, C / 32), dim3(32, 8), 0, stream>>>(w_qkv, wqkvt, C, NQKV);
    transpose_cvt<<<dim3(C / 32, C / 32), dim3(32, 8), 0, stream>>>(w_proj, wprojt, C, C);

    gemm_mfma<true ><<<dim3(NQKV / 128, M / 128), 256, 0, stream>>>(xb, wqkvt, b_qkv, qkvb, NQKV, C);
    attn_mfma<<<dim3(T / 64, Bb * H), 256, 0, stream>>>(qkvb, attb);
    gemm_mfma<false><<<dim3(C / 128, M / 128), 256, 0, stream>>>(attb, wprojt, b_proj, out, C, C);
}

// Round 4
// 220.803 us; speedup vs baseline: 6.8002x; 1.2708x over previous
//
#include <hip/hip_runtime.h>
#include <hip/hip_bf16.h>
#include <math.h>

// Problem constants (reference: B=2, T=2048, D_MODEL=1024, N_HEAD=16, D_HEAD=64)
constexpr int Bb   = 2;
constexpr int T    = 2048;
constexpr int C    = 1024;
constexpr int H    = 16;
constexpr int M    = Bb * T;   // 4096 rows
constexpr int NQKV = 3 * C;    // 3072

typedef __attribute__((ext_vector_type(8))) short bf16x8;
typedef __attribute__((ext_vector_type(4))) float f32x4;

__device__ inline short f2bf(float f) {
    __hip_bfloat16 h = __float2bfloat16(f);
    return *reinterpret_cast<short*>(&h);
}

#define GLOBAL_AS __attribute__((address_space(1)))
#define LDS_AS    __attribute__((address_space(3)))

// async global->LDS, 16B per lane; LDS dest must be wave-uniform base (lane i lands at base + i*16B)
__device__ __forceinline__ void gload_lds16(const short* g, short* s) {
    __builtin_amdgcn_global_load_lds((const GLOBAL_AS void*)g, (LDS_AS void*)s, 16, 0, 0);
}

// ---------------------------------------------------------------------------
// fp32 -> bf16 elementwise
// ---------------------------------------------------------------------------
__global__ __launch_bounds__(256)
void cvt_bf16(const float* __restrict__ x, short* __restrict__ y, int n)
{
    int i = (blockIdx.x * 256 + threadIdx.x) * 4;
    if (i < n) {
        const float4 v = *(const float4*)(x + i);
        short4 s;
        s.x = f2bf(v.x); s.y = f2bf(v.y); s.z = f2bf(v.z); s.w = f2bf(v.w);
        *(short4*)(y + i) = s;
    }
}

// ---------------------------------------------------------------------------
// W[K][N] fp32  ->  Wt[N][K] bf16   (32x32 LDS tile transpose)
// ---------------------------------------------------------------------------
__global__ __launch_bounds__(256)
void transpose_cvt(const float* __restrict__ W, short* __restrict__ Wt, int K, int N)
{
    __shared__ float tile[32][33];
    const int n0 = blockIdx.x * 32, k0 = blockIdx.y * 32;
    const int tx = threadIdx.x, ty = threadIdx.y;   // 32 x 8
#pragma unroll
    for (int i = 0; i < 32; i += 8)
        tile[ty + i][tx] = W[(size_t)(k0 + ty + i) * N + n0 + tx];
    __syncthreads();
#pragma unroll
    for (int i = 0; i < 32; i += 8)
        Wt[(size_t)(n0 + ty + i) * K + k0 + tx] = f2bf(tile[tx][ty + i]);
}

// ---------------------------------------------------------------------------
// out[M,N] = A[M,K] @ Bt[N,K]^T + bias[N]   (bf16 MFMA, 128x128 tile, BK=32)
// m97-style: staging via global_load_lds dwordx4, unpadded [128][32] LDS tiles.
// 4 waves, each a 64x64 subtile = 4x4 mfma_f32_16x16x32_bf16.
// ---------------------------------------------------------------------------
template<bool OUT_BF16>
__global__ __launch_bounds__(256)
void gemm_mfma(const short* __restrict__ A, const short* __restrict__ Bt,
               const float* __restrict__ bias, void* __restrict__ outp,
               int Ndim, int Kdim)
{
    __shared__ __align__(16) short As[128 * 32];
    __shared__ __align__(16) short Bs[128 * 32];

    const int tid = threadIdx.x;
    const int w   = tid >> 6;
    const int l   = tid & 63;
    const int lk  = l & 15;
    const int lq  = l >> 4;
    const int m0  = blockIdx.y * 128, n0 = blockIdx.x * 128;
    const int mw  = (w >> 1) * 64, nw = (w & 1) * 64;

    // staging map: wave w covers rows [w*16, w*16+16) (and +64); lane i -> row w*16+i/4, chunk (i%4)*8
    const int srow = w * 16 + (l >> 2);
    const int scol = (l & 3) * 8;
    short* asdst0 = &As[w * 512];          // wave-uniform
    short* asdst1 = &As[2048 + w * 512];
    short* bsdst0 = &Bs[w * 512];
    short* bsdst1 = &Bs[2048 + w * 512];

    f32x4 acc[4][4];
#pragma unroll
    for (int i = 0; i < 4; ++i)
#pragma unroll
        for (int j = 0; j < 4; ++j) acc[i][j] = (f32x4){0.f, 0.f, 0.f, 0.f};

    for (int k0 = 0; k0 < Kdim; k0 += 32) {
        __syncthreads();
        gload_lds16(A  + (size_t)(m0 + srow)      * Kdim + k0 + scol, asdst0);
        gload_lds16(A  + (size_t)(m0 + 64 + srow) * Kdim + k0 + scol, asdst1);
        gload_lds16(Bt + (size_t)(n0 + srow)      * Kdim + k0 + scol, bsdst0);
        gload_lds16(Bt + (size_t)(n0 + 64 + srow) * Kdim + k0 + scol, bsdst1);
        __syncthreads();

        bf16x8 af[4], bfr[4];
#pragma unroll
        for (int mt = 0; mt < 4; ++mt)
            af[mt] = *(const bf16x8*)&As[(mw + mt * 16 + lk) * 32 + lq * 8];
#pragma unroll
        for (int nt = 0; nt < 4; ++nt)
            bfr[nt] = *(const bf16x8*)&Bs[(nw + nt * 16 + lk) * 32 + lq * 8];
#pragma unroll
        for (int mt = 0; mt < 4; ++mt)
#pragma unroll
            for (int nt = 0; nt < 4; ++nt)
                acc[mt][nt] = __builtin_amdgcn_mfma_f32_16x16x32_bf16(af[mt], bfr[nt], acc[mt][nt], 0, 0, 0);
    }

#pragma unroll
    for (int mt = 0; mt < 4; ++mt) {
#pragma unroll
        for (int nt = 0; nt < 4; ++nt) {
            const int col = n0 + nw + nt * 16 + lk;
            const float bv = bias[col];
#pragma unroll
            for (int r = 0; r < 4; ++r) {
                const int row = m0 + mw + mt * 16 + lq * 4 + r;
                const float v = acc[mt][nt][r] + bv;
                if (OUT_BF16) ((short*)outp)[(size_t)row * Ndim + col] = f2bf(v);
                else          ((float*)outp)[(size_t)row * Ndim + col] = v;
            }
        }
    }
}

// ---------------------------------------------------------------------------
// MFMA flash attention v2: key-tile 128, paired q-tiles for load balance.
// Block = 4 waves; wave w owns q-rows [qt*64 + w*16, +16).
// blockIdx.x = x in [0,16): processes qt=x then qt=31-x  (uniform 17 iters).
// Ks [key][d] (LD 72); Vt [d][key] (LD 136, b64 4-key packed transpose);
// Ps per-wave [q][key] for the C->A layout round-trip.
// ---------------------------------------------------------------------------
constexpr int LDKS = 72;    // dims 64 + 8 pad (144 B rows)
constexpr int LDVT = 136;   // keys 128 + 8 pad (272 B rows)

__global__ __launch_bounds__(256)
void attn_mfma(const short* __restrict__ qkv, short* __restrict__ att)
{
    __shared__ __align__(16) short Ks[128 * LDKS];      // 18.4 KB
    __shared__ __align__(16) short Vt[64 * LDVT];       // 17.4 KB
    __shared__ __align__(16) short Ps[4][16 * LDVT];    // 17.4 KB

    const int tid = threadIdx.x;
    const int w   = tid >> 6;
    const int l   = tid & 63;
    const int lk  = l & 15;
    const int lq  = l >> 4;
    const int b   = blockIdx.y >> 4;
    const int h   = blockIdx.y & 15;

    const short* base = qkv + (size_t)b * T * 3072 + h * 64;

    // staging maps
    const int ksk = tid >> 1;            // 0..127: key for K staging
    const int ksd = (tid & 1) * 32;      // dim base (32 dims per thread)
    const int vg  = tid & 31;            // V key-group (4 consecutive keys)
    const int vsd = (tid >> 5) * 8;      // V dim base (8 dims per thread)

#pragma unroll 1
    for (int pass = 0; pass < 2; ++pass) {
        const int qt    = (pass == 0) ? (int)blockIdx.x : (31 - (int)blockIdx.x);
        const int qbase = qt * 64;

        // Q fragments (A-operand), loaded once per pass
        const short* qp = base + (size_t)(qbase + w * 16 + lk) * 3072 + lq * 8;
        const bf16x8 qf0 = *(const bf16x8*)qp;
        const bf16x8 qf1 = *(const bf16x8*)(qp + 32);

        f32x4 acc_o[4];
#pragma unroll
        for (int dt = 0; dt < 4; ++dt) acc_o[dt] = (f32x4){0.f, 0.f, 0.f, 0.f};
        float m_r[4] = {-INFINITY, -INFINITY, -INFINITY, -INFINITY};
        float l_r[4] = {0.f, 0.f, 0.f, 0.f};

        const int nkt = (qbase + 64 + 127) / 128;
#pragma unroll 1
        for (int it = 0; it < nkt; ++it) {
            const int j0 = it * 128;
            __syncthreads();
            {
                // K: [key][d] vector stores
                const short* kp = base + 1024 + (size_t)(j0 + ksk) * 3072 + ksd;
                const bf16x8 k0v = *(const bf16x8*)(kp + 0);
                const bf16x8 k1v = *(const bf16x8*)(kp + 8);
                const bf16x8 k2v = *(const bf16x8*)(kp + 16);
                const bf16x8 k3v = *(const bf16x8*)(kp + 24);
                *(bf16x8*)&Ks[ksk * LDKS + ksd + 0]  = k0v;
                *(bf16x8*)&Ks[ksk * LDKS + ksd + 8]  = k1v;
                *(bf16x8*)&Ks[ksk * LDKS + ksd + 16] = k2v;
                *(bf16x8*)&Ks[ksk * LDKS + ksd + 24] = k3v;
                // V: transpose 4 keys x 8 dims -> b64 packed writes
                const short* vp = base + 2048 + (size_t)(j0 + vg * 4) * 3072 + vsd;
                const bf16x8 v0 = *(const bf16x8*)(vp + 0 * 3072);
                const bf16x8 v1 = *(const bf16x8*)(vp + 1 * 3072);
                const bf16x8 v2 = *(const bf16x8*)(vp + 2 * 3072);
                const bf16x8 v3 = *(const bf16x8*)(vp + 3 * 3072);
#pragma unroll
                for (int j = 0; j < 8; ++j) {
                    short4 pk;
                    pk.x = v0[j]; pk.y = v1[j]; pk.z = v2[j]; pk.w = v3[j];
                    *(short4*)&Vt[(vsd + j) * LDVT + vg * 4] = pk;
                }
            }
            __syncthreads();

            // S = Q K^T over 8 key-subtiles of 16
            f32x4 s[8];
#pragma unroll
            for (int kt = 0; kt < 8; ++kt) {
                const bf16x8 kf0 = *(const bf16x8*)&Ks[(kt * 16 + lk) * LDKS + lq * 8];
                const bf16x8 kf1 = *(const bf16x8*)&Ks[(kt * 16 + lk) * LDKS + 32 + lq * 8];
                f32x4 a = (f32x4){0.f, 0.f, 0.f, 0.f};
                a = __builtin_amdgcn_mfma_f32_16x16x32_bf16(qf0, kf0, a, 0, 0, 0);
                a = __builtin_amdgcn_mfma_f32_16x16x32_bf16(qf1, kf1, a, 0, 0, 0);
                s[kt] = a;
            }

            // scale + causal mask (only tiles that can cross the diagonal)
            const bool needMask = (j0 + 127 > qbase);
            if (needMask) {
#pragma unroll
                for (int kt = 0; kt < 8; ++kt) {
#pragma unroll
                    for (int r = 0; r < 4; ++r) {
                        float sv = s[kt][r] * 0.125f;
                        if (j0 + kt * 16 + lk > qbase + w * 16 + lq * 4 + r) sv = -1e30f;
                        s[kt][r] = sv;
                    }
                }
            } else {
#pragma unroll
                for (int kt = 0; kt < 8; ++kt)
#pragma unroll
                    for (int r = 0; r < 4; ++r) s[kt][r] *= 0.125f;
            }

            // online softmax (rows live across 16 lanes)
            float corr[4];
#pragma unroll
            for (int r = 0; r < 4; ++r) {
                float mx = s[0][r];
#pragma unroll
                for (int kt = 1; kt < 8; ++kt) mx = fmaxf(mx, s[kt][r]);
                mx = fmaxf(mx, __shfl_xor(mx, 1));
                mx = fmaxf(mx, __shfl_xor(mx, 2));
                mx = fmaxf(mx, __shfl_xor(mx, 4));
                mx = fmaxf(mx, __shfl_xor(mx, 8));
                const float mn = fmaxf(m_r[r], mx);
                corr[r] = __expf(m_r[r] - mn);
                m_r[r]  = mn;
                float ps = 0.f;
#pragma unroll
                for (int kt = 0; kt < 8; ++kt) {
                    const float p = __expf(s[kt][r] - mn);
                    s[kt][r] = p;
                    ps += p;
                }
                ps += __shfl_xor(ps, 1);
                ps += __shfl_xor(ps, 2);
                ps += __shfl_xor(ps, 4);
                ps += __shfl_xor(ps, 8);
                l_r[r] = l_r[r] * corr[r] + ps;
            }

            // P: C-layout -> per-wave LDS -> A-layout
            short* myP = &Ps[w][0];
#pragma unroll
            for (int kt = 0; kt < 8; ++kt) {
#pragma unroll
                for (int r = 0; r < 4; ++r)
                    myP[(lq * 4 + r) * LDVT + kt * 16 + lk] = f2bf(s[kt][r]);
            }

#pragma unroll
            for (int dt = 0; dt < 4; ++dt) {
#pragma unroll
                for (int r = 0; r < 4; ++r) acc_o[dt][r] *= corr[r];
            }

            // O += P V   (128 keys as four 32-key chunks)
#pragma unroll
            for (int kc = 0; kc < 4; ++kc) {
                const bf16x8 pf = *(const bf16x8*)&myP[lk * LDVT + kc * 32 + lq * 8];
#pragma unroll
                for (int dt = 0; dt < 4; ++dt) {
                    const bf16x8 vf = *(const bf16x8*)&Vt[(dt * 16 + lk) * LDVT + kc * 32 + lq * 8];
                    acc_o[dt] = __builtin_amdgcn_mfma_f32_16x16x32_bf16(pf, vf, acc_o[dt], 0, 0, 0);
                }
            }
        }

        // epilogue: normalize, store bf16 [B,T,C] head-concat
        short* op = att + ((size_t)(b * T + qbase + w * 16)) * 1024 + h * 64;
#pragma unroll
        for (int r = 0; r < 4; ++r) {
            const float inv = 1.f / l_r[r];
#pragma unroll
            for (int dt = 0; dt < 4; ++dt)
                op[(size_t)(lq * 4 + r) * 1024 + dt * 16 + lk] = f2bf(acc_o[dt][r] * inv);
        }
    }
}

// ---------------------------------------------------------------------------
extern "C" void kernel_launch(void* const* d_in, const int* in_sizes, int n_in,
                              void* d_out, int out_size, void* d_ws, size_t ws_size,
                              hipStream_t stream)
{
    const float* x      = (const float*)d_in[0];   // [B,T,C]
    const float* w_qkv  = (const float*)d_in[1];   // [C,3C]
    const float* b_qkv  = (const float*)d_in[2];   // [3C]
    const float* w_proj = (const float*)d_in[3];   // [C,C]
    const float* b_proj = (const float*)d_in[4];   // [C]
    float* out = (float*)d_out;                    // [B,T,C] fp32

    short* xb     = (short*)d_ws;                        //  8 MB
    short* wqkvt  = xb     + (size_t)M * C;              //  6 MB  [3072][1024]
    short* wprojt = wqkvt  + (size_t)NQKV * C;           //  2 MB  [1024][1024]
    short* qkvb   = wprojt + (size_t)C * C;              // 24 MB  [4096][3072]
    short* attb   = qkvb   + (size_t)M * NQKV;           //  8 MB  [4096][1024]

    cvt_bf16<<<(M * C) / 1024, 256, 0, stream>>>(x, xb, M * C);
    transpose_cvt<<<dim3(NQKV / 32, C / 32), dim3(32, 8), 0, stream>>>(w_qkv, wqkvt, C, NQKV);
    transpose_cvt<<<dim3(C / 32, C / 32), dim3(32, 8), 0, stream>>>(w_proj, wprojt, C, C);

    gemm_mfma<true ><<<dim3(NQKV / 128, M / 128), 256, 0, stream>>>(xb, wqkvt, b_qkv, qkvb, NQKV, C);
    attn_mfma<<<dim3(T / 128, Bb * H), 256, 0, stream>>>(qkvb, attb);
    gemm_mfma<false><<<dim3(C / 128, M / 128), 256, 0, stream>>>(attb, wprojt, b_proj, out, C, C);
}